// Round 1
// baseline (42.120 us; speedup 1.0000x reference)
//
#include <hip/hip_runtime.h>
#include <math.h>

#define DD 15          // feature dim
#define DP 20          // padded row stride (floats): 80B, float4-aligned, 4-bank spread
#define LL 64          // leaves
#define NCC 10         // num classes
#define TL 127         // tree length

__global__ __launch_bounds__(64) void seg_tree_kernel(
    const float* __restrict__ emb,
    const float* __restrict__ W_lin,
    const float* __restrict__ W_rule,
    const int*  __restrict__ x,
    const int*  __restrict__ qlo_g,
    const int*  __restrict__ qhi_g,
    float* __restrict__ out)
{
    __shared__ __align__(16) float nemb[NCC + 1][DP];
    __shared__ __align__(16) float tree[TL][DP];
    __shared__ __align__(16) float Wr[2][DD][16];   // padded W rows; broadcast reads
    __shared__ float logits[64];

    const int t = threadIdx.x;
    const int b = blockIdx.x;

    // ---- load W_rule into LDS (padded rows) ----
    for (int m = t; m < 2 * DD * DD; m += 64) {
        int k = m / (DD * DD);
        int r = m - k * DD * DD;
        int i = r / DD;
        int j = r - i * DD;
        Wr[k][i][j] = W_rule[m];
    }
    // ---- normalize emb rows (row 10 = inf_n) ----
    if (t < NCC + 1) {
        float v[DD]; float ss = 0.f;
        #pragma unroll
        for (int d = 0; d < DD; ++d) { v[d] = emb[t * DD + d]; ss += v[d] * v[d]; }
        float inv = 1.0f / (sqrtf(ss * (1.0f / DD) + 1e-6f) + 1e-6f);
        #pragma unroll
        for (int d = 0; d < DD; ++d) nemb[t][d] = v[d] * inv;
    }
    __syncthreads();

    // ---- leaves: tree[63+i] = nemb[x[b,i]] ----
    {
        int xi = x[b * LL + t];
        #pragma unroll
        for (int d = 0; d < DD; ++d) tree[63 + t][d] = nemb[xi][d];
    }
    __syncthreads();

    // ---- build: bottom-up combine ----
    for (int lvl = 5; lvl >= 0; --lvl) {
        int n = 1 << lvl, first = n - 1;
        if (t < 2 * n) {
            int p = first + (t >> 1);
            int k = t & 1;
            float A[DD], Bv[DD];
            #pragma unroll
            for (int d = 0; d < DD; ++d) { A[d] = tree[2 * p + 1][d]; Bv[d] = tree[2 * p + 2][d]; }
            float acc = 0.f;
            for (int i = 0; i < DD; ++i) {
                float ai = A[i];
                #pragma unroll
                for (int j = 0; j < DD; ++j)
                    acc += ai * Bv[j] * Wr[k][i][j];
            }
            logits[t] = acc;
        }
        __syncthreads();
        if (t < n) {
            int p = first + t;
            float l0 = logits[2 * t], l1 = logits[2 * t + 1];
            float mx = fmaxf(l0, l1);
            float e0 = __expf(l0 - mx), e1 = __expf(l1 - mx);
            float sden = e0 + e1;
            float a0 = e0 / sden, a1 = e1 / sden;
            float v[DD]; float ss = 0.f;
            #pragma unroll
            for (int d = 0; d < DD; ++d) {
                v[d] = a0 * tree[2 * p + 1][d] + a1 * tree[2 * p + 2][d];
                ss += v[d] * v[d];
            }
            float inv = 1.0f / (sqrtf(ss * (1.0f / DD) + 1e-6f) + 1e-6f);
            #pragma unroll
            for (int d = 0; d < DD; ++d) tree[p][d] = v[d] * inv;
        }
        __syncthreads();
    }

    // ---- query: Q computed in-place bottom-up ----
    const int ql = qlo_g[b], qh = qhi_g[b];
    // leaves
    {
        bool inr = (ql <= t) && (qh >= t);
        if (!inr) {
            #pragma unroll
            for (int d = 0; d < DD; ++d) tree[63 + t][d] = nemb[NCC][d];
        }
    }
    __syncthreads();

    for (int lvl = 5; lvl >= 0; --lvl) {
        int n = 1 << lvl, first = n - 1;
        int s = LL >> lvl;
        if (t < 2 * n) {
            int p = first + (t >> 1);
            int k = t & 1;
            float A[DD], Bv[DD];
            #pragma unroll
            for (int d = 0; d < DD; ++d) { A[d] = tree[2 * p + 1][d]; Bv[d] = tree[2 * p + 2][d]; }
            float acc = 0.f;
            for (int i = 0; i < DD; ++i) {
                float ai = A[i];
                #pragma unroll
                for (int j = 0; j < DD; ++j)
                    acc += ai * Bv[j] * Wr[k][i][j];
            }
            logits[t] = acc;
        }
        __syncthreads();
        if (t < n) {
            int p = first + t;
            int lo = t * s, hi = lo + s - 1;
            bool full = (ql <= lo) && (qh >= hi);
            bool disj = (ql > hi) || (qh < lo);
            if (disj) {
                #pragma unroll
                for (int d = 0; d < DD; ++d) tree[p][d] = nemb[NCC][d];
            } else if (!full) {
                float l0 = logits[2 * t], l1 = logits[2 * t + 1];
                float mx = fmaxf(l0, l1);
                float e0 = __expf(l0 - mx), e1 = __expf(l1 - mx);
                float sden = e0 + e1;
                float a0 = e0 / sden, a1 = e1 / sden;
                float v[DD]; float ss = 0.f;
                #pragma unroll
                for (int d = 0; d < DD; ++d) {
                    v[d] = a0 * tree[2 * p + 1][d] + a1 * tree[2 * p + 2][d];
                    ss += v[d] * v[d];
                }
                float inv = 1.0f / (sqrtf(ss * (1.0f / DD) + 1e-6f) + 1e-6f);
                #pragma unroll
                for (int d = 0; d < DD; ++d) tree[p][d] = v[d] * inv;
            }
            // full: keep tree[p] (already normalized)
        }
        __syncthreads();
    }

    // ---- output: out[b] = Q(root) @ W_lin.T ----
    if (t < NCC) {
        float acc = 0.f;
        #pragma unroll
        for (int d = 0; d < DD; ++d) acc += tree[0][d] * W_lin[t * DD + d];
        out[b * NCC + t] = acc;
    }
}

extern "C" void kernel_launch(void* const* d_in, const int* in_sizes, int n_in,
                              void* d_out, int out_size, void* d_ws, size_t ws_size,
                              hipStream_t stream) {
    const float* emb    = (const float*)d_in[0];
    const float* W_lin  = (const float*)d_in[1];
    const float* W_rule = (const float*)d_in[2];
    const int*   x      = (const int*)d_in[3];
    const int*   qlo    = (const int*)d_in[4];
    const int*   qhi    = (const int*)d_in[5];
    float* outp = (float*)d_out;

    int bsz = in_sizes[3] / LL;   // 2048
    seg_tree_kernel<<<dim3(bsz), dim3(64), 0, stream>>>(
        emb, W_lin, W_rule, x, qlo, qhi, outp);
}

// Round 2
// 24.867 us; speedup vs baseline: 1.6938x; 1.6938x over previous
//
#include <hip/hip_runtime.h>
#include <math.h>

#define DD 15          // feature dim
#define DP 17          // padded LDS row stride (odd -> 2-way max bank aliasing)
#define LL 64          // leaves
#define NCC 10         // num classes
#define TL 127         // tree length

__global__ __launch_bounds__(64) void seg_tree_kernel(
    const float* __restrict__ emb,
    const float* __restrict__ W_lin,
    const float* __restrict__ W_rule,
    const int*  __restrict__ x,
    const int*  __restrict__ qlo_g,
    const int*  __restrict__ qhi_g,
    float* __restrict__ out)
{
    __shared__ float nemb[NCC + 1][DP];
    __shared__ float tree[TL][DP];

    const int t  = threadIdx.x;
    const int b  = blockIdx.x;
    const int k  = t & 1;          // which W_rule matrix
    const int h  = (t >> 1) & 1;   // row-half of the matrix
    const int qq = t & 3;          // lane-in-group (dims assignment for mix)
    const int g  = t >> 2;         // group id: 16 parents per wave-step

    // ---- per-lane weight residency: rows 8h..8h+7 of W_rule[k] (120 VGPRs) ----
    float w[8][DD];
    #pragma unroll
    for (int ri = 0; ri < 8; ++ri) {
        int i = 8 * h + ri;
        bool valid = (i < DD);
        const float* src = W_rule + k * DD * DD + (valid ? i * DD : 0);
        #pragma unroll
        for (int j = 0; j < DD; ++j)
            w[ri][j] = valid ? src[j] : 0.0f;   // zero row kills the padded i=15
    }

    // ---- normalize emb rows into LDS (row NCC = normalized inf vector) ----
    if (t < NCC + 1) {
        float v[DD]; float ss = 0.f;
        #pragma unroll
        for (int d = 0; d < DD; ++d) { v[d] = emb[t * DD + d]; ss += v[d] * v[d]; }
        float inv = 1.0f / (sqrtf(ss * (1.0f / DD) + 1e-6f) + 1e-6f);
        #pragma unroll
        for (int d = 0; d < DD; ++d) nemb[t][d] = v[d] * inv;
    }
    __syncthreads();

    // ---- leaves ----
    {
        int xi = x[b * LL + t];
        #pragma unroll
        for (int d = 0; d < DD; ++d) tree[63 + t][d] = nemb[xi][d];
    }
    __syncthreads();

    // combine for parent p: 4 lanes cooperate; returns premix v[4] and rms inv
    auto combine_vals = [&](int p, float v[4], float& inv) {
        float Bv[DD];
        #pragma unroll
        for (int j = 0; j < DD; ++j) Bv[j] = tree[2 * p + 2][j];  // group-broadcast
        float acc = 0.f;
        #pragma unroll
        for (int ri = 0; ri < 8; ++ri) {
            int i = 8 * h + ri; if (i > DD - 1) i = DD - 1;        // clamped; w row is 0
            float Ai = tree[2 * p + 1][i];
            float dot = 0.f;
            #pragma unroll
            for (int j = 0; j < DD; ++j) dot = fmaf(w[ri][j], Bv[j], dot);
            acc = fmaf(Ai, dot, acc);
        }
        acc += __shfl_xor(acc, 2);                 // reduce over row-halves
        float lo_ = __shfl_xor(acc, 1);            // partner logit (other k)
        float mx = fmaxf(acc, lo_);
        float es = __expf(acc - mx), eo = __expf(lo_ - mx);
        float rs = 1.0f / (es + eo);
        float a_self = es * rs, a_oth = eo * rs;
        float alpha0 = (k == 0) ? a_self : a_oth;
        float alpha1 = (k == 0) ? a_oth  : a_self;
        float ss = 0.f;
        #pragma unroll
        for (int m = 0; m < 4; ++m) {
            int d = qq * 4 + m; int dc = (d < DD) ? d : DD - 1;
            float val = alpha0 * tree[2 * p + 1][dc] + alpha1 * tree[2 * p + 2][dc];
            v[m] = val;
            ss += (d < DD) ? val * val : 0.f;
        }
        ss += __shfl_xor(ss, 1);
        ss += __shfl_xor(ss, 2);
        inv = 1.0f / (sqrtf(ss * (1.0f / DD) + 1e-6f) + 1e-6f);
    };

    // ---- build: bottom-up, 16 parents per step ----
    for (int lvl = 5; lvl >= 0; --lvl) {
        int n = 1 << lvl, first = n - 1;
        for (int base = 0; base < n; base += 16) {
            int pi = base + g;
            if (pi < n) {
                int p = first + pi;
                float v[4], inv;
                combine_vals(p, v, inv);
                #pragma unroll
                for (int m = 0; m < 4; ++m) {
                    int d = qq * 4 + m;
                    if (d < DD) tree[p][d] = v[m] * inv;
                }
            }
        }
        __syncthreads();
    }

    // ---- query: in-place bottom-up ----
    const int ql = qlo_g[b], qh = qhi_g[b];
    {
        bool inr = (ql <= t) && (qh >= t);
        if (!inr) {
            #pragma unroll
            for (int d = 0; d < DD; ++d) tree[63 + t][d] = nemb[NCC][d];
        }
    }
    __syncthreads();

    for (int lvl = 5; lvl >= 0; --lvl) {
        int n = 1 << lvl, first = n - 1, s = LL >> lvl;
        for (int base = 0; base < n; base += 16) {
            int pi = base + g;
            if (pi < n) {
                int p = first + pi;
                int lo = pi * s, hi = lo + s - 1;
                bool full = (ql <= lo) && (qh >= hi);
                bool disj = (ql > hi) || (qh < lo);
                float v[4], inv;
                combine_vals(p, v, inv);
                if (disj) {
                    #pragma unroll
                    for (int m = 0; m < 4; ++m) {
                        int d = qq * 4 + m;
                        if (d < DD) tree[p][d] = nemb[NCC][d];
                    }
                } else if (!full) {
                    #pragma unroll
                    for (int m = 0; m < 4; ++m) {
                        int d = qq * 4 + m;
                        if (d < DD) tree[p][d] = v[m] * inv;
                    }
                }
                // full: keep tree[p]
            }
        }
        __syncthreads();
    }

    // ---- output: out[b] = Q(root) @ W_lin.T ----
    if (t < NCC) {
        float acc = 0.f;
        #pragma unroll
        for (int d = 0; d < DD; ++d) acc = fmaf(tree[0][d], W_lin[t * DD + d], acc);
        out[b * NCC + t] = acc;
    }
}

extern "C" void kernel_launch(void* const* d_in, const int* in_sizes, int n_in,
                              void* d_out, int out_size, void* d_ws, size_t ws_size,
                              hipStream_t stream) {
    const float* emb    = (const float*)d_in[0];
    const float* W_lin  = (const float*)d_in[1];
    const float* W_rule = (const float*)d_in[2];
    const int*   x      = (const int*)d_in[3];
    const int*   qlo    = (const int*)d_in[4];
    const int*   qhi    = (const int*)d_in[5];
    float* outp = (float*)d_out;

    int bsz = in_sizes[3] / LL;   // 2048
    seg_tree_kernel<<<dim3(bsz), dim3(64), 0, stream>>>(
        emb, W_lin, W_rule, x, qlo, qhi, outp);
}

// Round 3
// 18.831 us; speedup vs baseline: 2.2367x; 1.3205x over previous
//
#include <hip/hip_runtime.h>
#include <math.h>

#define DD 15          // feature dim
#define DP 20          // padded LDS row stride (80B, float4-aligned)
#define LL 64          // leaves
#define NCC 10         // num classes
#define TL 127         // tree length

// DPP quad-perm lane swaps (VALU, ~1cy; no LDS pipe)
__device__ __forceinline__ float dpp_xor1(float x) {   // lane ^= 1 (quad_perm [1,0,3,2])
    return __int_as_float(__builtin_amdgcn_update_dpp(0, __float_as_int(x), 177, 0xF, 0xF, true));
}
__device__ __forceinline__ float dpp_xor2(float x) {   // lane ^= 2 (quad_perm [2,3,0,1])
    return __int_as_float(__builtin_amdgcn_update_dpp(0, __float_as_int(x), 78, 0xF, 0xF, true));
}
__device__ __forceinline__ float swz_xor4(float x) {   // lane ^= 4 via ds_swizzle BitMode
    return __int_as_float(__builtin_amdgcn_ds_swizzle(__float_as_int(x), 0x101F));
}

__device__ __forceinline__ float fast_rcp(float x)  { return __builtin_amdgcn_rcpf(x); }
__device__ __forceinline__ float fast_sqrt(float x) { return __builtin_amdgcn_sqrtf(x); }

// combine at parent p: 8 lanes cooperate (k = t&1 picks W matrix, qr = rows, u = dims)
__device__ __forceinline__ void combine8(const float (*tree)[DP], const float w[4][DD],
                                         int k, int qr, int u, int p,
                                         float& v0, float& v1, float& inv)
{
    const float* Lrow = &tree[2 * p + 1][0];
    const float* Rrow = &tree[2 * p + 2][0];
    float4 R0 = ((const float4*)Rrow)[0];
    float4 R1 = ((const float4*)Rrow)[1];
    float4 R2 = ((const float4*)Rrow)[2];
    float4 R3 = ((const float4*)Rrow)[3];           // .w = pad col15 = 0
    float4 Aq = ((const float4*)Lrow)[qr];          // L dims 4qr..4qr+3 (pad = 0)
    float Bv[DD] = {R0.x,R0.y,R0.z,R0.w, R1.x,R1.y,R1.z,R1.w,
                    R2.x,R2.y,R2.z,R2.w, R3.x,R3.y,R3.z};
    float Av[4] = {Aq.x, Aq.y, Aq.z, Aq.w};

    float acc = 0.f;
    #pragma unroll
    for (int ri = 0; ri < 4; ++ri) {
        float d0 = 0.f;
        #pragma unroll
        for (int j = 0; j < DD; ++j) d0 = fmaf(w[ri][j], Bv[j], d0);
        acc = fmaf(Av[ri], d0, acc);                // row 15: w==0, Av==0 -> 0
    }
    // reduce partial logits over qr (t-bits 1,2); then fetch partner-k logit
    acc += dpp_xor2(acc);
    acc += swz_xor4(acc);
    float oth = dpp_xor1(acc);
    float mx = fmaxf(acc, oth);
    float es = __expf(acc - mx), eo = __expf(oth - mx);
    float rs = fast_rcp(es + eo);
    float aS = es * rs, aO = eo * rs;
    float a0 = (k == 0) ? aS : aO;
    float a1 = (k == 0) ? aO : aS;

    // mix: lane u handles dims 2u, 2u+1 (dim 15 = pad = 0 -> contributes 0)
    float2 lm = ((const float2*)Lrow)[u];
    float2 rm = ((const float2*)Rrow)[u];
    v0 = a0 * lm.x + a1 * rm.x;
    v1 = a0 * lm.y + a1 * rm.y;
    float ss = v0 * v0 + v1 * v1;
    ss += dpp_xor1(ss);
    ss += dpp_xor2(ss);
    ss += swz_xor4(ss);
    inv = fast_rcp(fast_sqrt(ss * (1.0f / DD) + 1e-6f) + 1e-6f);
}

template<int LVL, bool QUERY>
__device__ __forceinline__ void do_level(float (*tree)[DP], const float (*nemb)[DP],
                                         const float w[4][DD], int t, int ql, int qh)
{
    constexpr int n = 1 << LVL, first = n - 1, nst = (n + 7) / 8, s = LL >> LVL;
    const int k = t & 1, qr = (t >> 1) & 3, u = t & 7, g = t >> 3;
    #pragma unroll
    for (int st = 0; st < nst; ++st) {
        int pi0 = st * 8 + g;
        int pi = (pi0 < n) ? pi0 : (n - 1);     // clamp so reads stay in-bounds
        int p = first + pi;
        float v0, v1, inv;
        combine8(tree, w, k, qr, u, p, v0, v1, inv);
        if constexpr (!QUERY) {
            if (pi0 < n)
                ((float2*)&tree[p][0])[u] = make_float2(v0 * inv, v1 * inv);
        } else {
            int lo = pi * s, hi = lo + s - 1;
            bool full = (ql <= lo) && (qh >= hi);
            bool disj = (ql > hi) || (qh < lo);
            if (pi0 < n && !full) {
                float2 wv;
                if (disj) wv = ((const float2*)&nemb[NCC][0])[u];
                else      wv = make_float2(v0 * inv, v1 * inv);
                ((float2*)&tree[p][0])[u] = wv;
            }
        }
    }
    __syncthreads();
}

extern "C" __global__ __attribute__((amdgpu_flat_work_group_size(64, 64)))
void seg_tree_kernel(
    const float* __restrict__ emb,
    const float* __restrict__ W_lin,
    const float* __restrict__ W_rule,
    const int*  __restrict__ x,
    const int*  __restrict__ qlo_g,
    const int*  __restrict__ qhi_g,
    float* __restrict__ out)
{
    __shared__ __align__(16) float nemb[NCC + 1][DP];
    __shared__ __align__(16) float tree[TL][DP];

    const int t = threadIdx.x;
    const int b = blockIdx.x;
    const int k = t & 1, qr = (t >> 1) & 3;

    // ---- per-lane weights: rows 4qr..4qr+3 of W_rule[k] (60 VGPRs; row 15 = 0) ----
    float w[4][DD];
    #pragma unroll
    for (int ri = 0; ri < 4; ++ri) {
        int i = 4 * qr + ri;
        bool valid = (i < DD);
        const float* src = W_rule + k * DD * DD + (valid ? i * DD : 0);
        #pragma unroll
        for (int j = 0; j < DD; ++j) w[ri][j] = valid ? src[j] : 0.0f;
    }

    // ---- normalize emb rows into LDS (row NCC = normalized inf); pad col15 = 0 ----
    if (t < NCC + 1) {
        float v[DD]; float ssum = 0.f;
        #pragma unroll
        for (int d = 0; d < DD; ++d) { v[d] = emb[t * DD + d]; ssum += v[d] * v[d]; }
        float inv = fast_rcp(fast_sqrt(ssum * (1.0f / DD) + 1e-6f) + 1e-6f);
        #pragma unroll
        for (int d = 0; d < DD; ++d) nemb[t][d] = v[d] * inv;
        nemb[t][DD] = 0.0f;                       // pad col 15 stays exactly 0
    }
    __syncthreads();

    // ---- leaves: tree[63+t] = nemb[x[b][t]] (cols 0..15, col15 = 0) ----
    {
        int xi = x[b * LL + t];
        #pragma unroll
        for (int j = 0; j < 4; ++j)
            ((float4*)&tree[63 + t][0])[j] = ((const float4*)&nemb[xi][0])[j];
    }
    __syncthreads();

    // ---- build ----
    do_level<5, false>(tree, nemb, w, t, 0, 0);
    do_level<4, false>(tree, nemb, w, t, 0, 0);
    do_level<3, false>(tree, nemb, w, t, 0, 0);
    do_level<2, false>(tree, nemb, w, t, 0, 0);
    do_level<1, false>(tree, nemb, w, t, 0, 0);
    do_level<0, false>(tree, nemb, w, t, 0, 0);

    // ---- query leaves: out-of-range -> normalized inf ----
    const int ql = qlo_g[b], qh = qhi_g[b];
    {
        bool inr = (ql <= t) && (qh >= t);
        if (!inr) {
            #pragma unroll
            for (int j = 0; j < 4; ++j)
                ((float4*)&tree[63 + t][0])[j] = ((const float4*)&nemb[NCC][0])[j];
        }
    }
    __syncthreads();

    // ---- query (in-place bottom-up) ----
    do_level<5, true>(tree, nemb, w, t, ql, qh);
    do_level<4, true>(tree, nemb, w, t, ql, qh);
    do_level<3, true>(tree, nemb, w, t, ql, qh);
    do_level<2, true>(tree, nemb, w, t, ql, qh);
    do_level<1, true>(tree, nemb, w, t, ql, qh);
    do_level<0, true>(tree, nemb, w, t, ql, qh);

    // ---- output: out[b] = Q(root) @ W_lin.T ----
    if (t < NCC) {
        float acc = 0.f;
        #pragma unroll
        for (int d = 0; d < DD; ++d) acc = fmaf(tree[0][d], W_lin[t * DD + d], acc);
        out[b * NCC + t] = acc;
    }
}

extern "C" void kernel_launch(void* const* d_in, const int* in_sizes, int n_in,
                              void* d_out, int out_size, void* d_ws, size_t ws_size,
                              hipStream_t stream) {
    const float* emb    = (const float*)d_in[0];
    const float* W_lin  = (const float*)d_in[1];
    const float* W_rule = (const float*)d_in[2];
    const int*   x      = (const int*)d_in[3];
    const int*   qlo    = (const int*)d_in[4];
    const int*   qhi    = (const int*)d_in[5];
    float* outp = (float*)d_out;

    int bsz = in_sizes[3] / LL;   // 2048
    seg_tree_kernel<<<dim3(bsz), dim3(64), 0, stream>>>(
        emb, W_lin, W_rule, x, qlo, qhi, outp);
}

// Round 4
// 16.326 us; speedup vs baseline: 2.5799x; 1.1535x over previous
//
#include <hip/hip_runtime.h>
#include <math.h>

#define DD 15          // feature dim
#define DP 20          // padded LDS row stride (80B, float4-aligned)
#define LL 64          // leaves
#define NCC 10         // num classes
#define TL 127         // tree length

// ---- DPP cross-lane (VALU pipe, no LDS) ----
__device__ __forceinline__ float dpp_xor1(float x) {   // quad_perm [1,0,3,2]
    return __int_as_float(__builtin_amdgcn_update_dpp(0, __float_as_int(x), 0xB1, 0xF, 0xF, true));
}
__device__ __forceinline__ float dpp_xor2(float x) {   // quad_perm [2,3,0,1]
    return __int_as_float(__builtin_amdgcn_update_dpp(0, __float_as_int(x), 0x4E, 0xF, 0xF, true));
}
__device__ __forceinline__ float dpp_hmirror(float x) { // row_half_mirror: u -> u^7 within 8
    return __int_as_float(__builtin_amdgcn_update_dpp(0, __float_as_int(x), 0x141, 0xF, 0xF, true));
}

// combine at one parent: 8 lanes cooperate.
// k = t&1 (which W matrix), qr = (t>>1)&3 (4 A-rows), u = t&7 (2 output dims)
__device__ __forceinline__ void combine8_core(const float* Lrow, const float* Rrow,
                                              const float w[4][DD], int k, int qr, int u,
                                              float& o0, float& o1)
{
    float4 R0 = ((const float4*)Rrow)[0];
    float4 R1 = ((const float4*)Rrow)[1];
    float4 R2 = ((const float4*)Rrow)[2];
    float4 R3 = ((const float4*)Rrow)[3];          // .w = pad col15 = 0
    float4 Aq = ((const float4*)Lrow)[qr];         // A dims 4qr..4qr+3 (row15 pad = 0)
    float Bv[DD] = {R0.x,R0.y,R0.z,R0.w, R1.x,R1.y,R1.z,R1.w,
                    R2.x,R2.y,R2.z,R2.w, R3.x,R3.y,R3.z};
    float Av[4] = {Aq.x, Aq.y, Aq.z, Aq.w};

    float p = 0.f;
    #pragma unroll
    for (int ri = 0; ri < 4; ++ri) {
        float d0 = 0.f;
        #pragma unroll
        for (int j = 0; j < DD; ++j) d0 = fmaf(w[ri][j], Bv[j], d0);
        p = fmaf(Av[ri], d0, p);                   // invalid row 15: w==0, Av==0
    }
    // per-lane partial p(k, qr). Reduce over qr (bits 1,2) for both k, all via DPP:
    float a   = p + dpp_xor2(p);                   // sum over bit1
    float hma = dpp_hmirror(a);                    // a at (k^1, b2^1)
    float self = a + dpp_xor1(hma);                // logit for own k
    float oth  = dpp_xor1(a) + hma;                // logit for other k
    float mx = fmaxf(self, oth);
    float es = __expf(self - mx), eo = __expf(oth - mx);
    float rs = __builtin_amdgcn_rcpf(es + eo);
    float aS = es * rs, aO = eo * rs;
    float a0 = (k == 0) ? aS : aO;                 // alpha for W0 (scales left child)
    float a1 = (k == 0) ? aO : aS;

    float2 lm = ((const float2*)Lrow)[u];          // dims 2u, 2u+1
    float2 rm = ((const float2*)Rrow)[u];
    float v0 = a0 * lm.x + a1 * rm.x;
    float v1 = a0 * lm.y + a1 * rm.y;              // u==7: dim15 = 0
    float ss = v0 * v0 + v1 * v1;
    ss += dpp_xor1(ss);
    ss += dpp_xor2(ss);
    ss += dpp_hmirror(ss);                         // full 8-lane sum, broadcast
    float inv = __builtin_amdgcn_rsqf(ss * (1.0f / DD) + 1e-6f);
    o0 = v0 * inv; o1 = v1 * inv;
}

template<int LVL>
__device__ __forceinline__ void build_level(float (*tree)[DP], const float w[4][DD],
                                            int k, int qr, int u, int g)
{
    constexpr int n = 1 << LVL, first = n - 1, nst = (n + 7) / 8;
    #pragma unroll
    for (int st = 0; st < nst; ++st) {
        int pi0 = st * 8 + g;
        int pi = (n < 8) ? ((pi0 < n) ? pi0 : 0) : pi0;   // clamp keeps reads in-bounds
        int p = first + pi;
        float o0, o1;
        combine8_core(&tree[2 * p + 1][0], &tree[2 * p + 2][0], w, k, qr, u, o0, o1);
        if (pi0 < n)
            ((float2*)&tree[p][0])[u] = make_float2(o0, o1);
    }
}

// Query: compute Q only for the <=2 partial nodes at this level (boundary paths).
// Child fetch: disjoint -> nemb[NCC]; else tree[child] (holds build value if full,
// Q value if partial — written last phase). Result overwrites tree[p].
template<int LVL>
__device__ __forceinline__ void query_level(float (*tree)[DP], const float (*nemb)[DP],
                                            const float w[4][DD], int t, int k, int qr, int u,
                                            int ql, int qh)
{
    constexpr int first = (1 << LVL) - 1;
    constexpr int sh = 6 - LVL;                    // node covers 1<<sh leaves
    constexpr int shc = sh - 1;
    const int g2 = (t >> 3) & 1;                   // 0 -> ql-path node, 1 -> qh-path node
    int bnd = g2 ? qh : ql;
    int pi = bnd >> sh;
    int lo = pi << sh, hi = lo + (1 << sh) - 1;
    bool full = (ql <= lo) && (qh >= hi);          // boundary node never disjoint
    int p = first + pi;
    int ci1 = 2 * pi, ci2 = 2 * pi + 1;            // children (level LVL+1; leaves if LVL==5)
    int lo1 = ci1 << shc, hi1 = lo1 + (1 << shc) - 1;
    int lo2 = ci2 << shc, hi2 = lo2 + (1 << shc) - 1;
    bool d1 = (ql > hi1) || (qh < lo1);
    bool d2 = (ql > hi2) || (qh < lo2);
    const float* Lrow = d1 ? &nemb[NCC][0] : &tree[2 * p + 1][0];
    const float* Rrow = d2 ? &nemb[NCC][0] : &tree[2 * p + 2][0];
    float o0, o1;
    combine8_core(Lrow, Rrow, w, k, qr, u, o0, o1);
    int pi_g0 = ql >> sh;
    bool we = (!full) && (t < 16) && (g2 == 0 || pi != pi_g0);
    if (we)
        ((float2*)&tree[p][0])[u] = make_float2(o0, o1);
}

extern "C" __global__ __attribute__((amdgpu_flat_work_group_size(64, 64)))
void seg_tree_kernel(
    const float* __restrict__ emb,
    const float* __restrict__ W_lin,
    const float* __restrict__ W_rule,
    const int*  __restrict__ x,
    const int*  __restrict__ qlo_g,
    const int*  __restrict__ qhi_g,
    float* __restrict__ out)
{
    __shared__ __align__(16) float nemb[NCC + 1][DP];
    __shared__ __align__(16) float tree[TL][DP];

    const int t = threadIdx.x;
    const int b = blockIdx.x;
    const int k = t & 1, qr = (t >> 1) & 3, u = t & 7, g = t >> 3;

    const int xi = x[b * LL + t];
    const int ql = qlo_g[b], qh = qhi_g[b];

    // ---- per-lane weights: rows 4qr..4qr+3 of W_rule[k]; row 15 zeroed. Pin in VGPRs. ----
    float w[4][DD];
    #pragma unroll
    for (int ri = 0; ri < 4; ++ri) {
        int i = 4 * qr + ri;
        bool valid = (i < DD);
        const float* src = W_rule + k * DD * DD + (valid ? i * DD : 0);
        #pragma unroll
        for (int j = 0; j < DD; ++j) w[ri][j] = valid ? src[j] : 0.0f;
    }
    #pragma unroll
    for (int ri = 0; ri < 4; ++ri)
        #pragma unroll
        for (int j = 0; j < DD; ++j)
            asm volatile("" : "+v"(w[ri][j]));

    // ---- W_lin row for the epilogue (lanes 0..9), pinned ----
    float wl[DD];
    {
        const float* wlp = W_lin + ((t < NCC) ? t : 0) * DD;
        #pragma unroll
        for (int d = 0; d < DD; ++d) wl[d] = wlp[d];
        #pragma unroll
        for (int d = 0; d < DD; ++d) asm volatile("" : "+v"(wl[d]));
    }

    // ---- normalize emb rows into LDS; pad col15 = 0 ----
    if (t < NCC + 1) {
        float v[DD]; float ssum = 0.f;
        #pragma unroll
        for (int d = 0; d < DD; ++d) { v[d] = emb[t * DD + d]; ssum += v[d] * v[d]; }
        float inv = __builtin_amdgcn_rsqf(ssum * (1.0f / DD) + 1e-6f);
        #pragma unroll
        for (int d = 0; d < DD; ++d) nemb[t][d] = v[d] * inv;
        nemb[t][DD] = 0.0f;
    }
    __syncthreads();

    // ---- leaves ----
    #pragma unroll
    for (int j = 0; j < 4; ++j)
        ((float4*)&tree[63 + t][0])[j] = ((const float4*)&nemb[xi][0])[j];
    __syncthreads();

    // ---- fused 7-phase schedule: ph_i = { build L(5-i) ; query L(6-i) } ----
    build_level<5>(tree, w, k, qr, u, g);
    __syncthreads();
    build_level<4>(tree, w, k, qr, u, g);
    query_level<5>(tree, nemb, w, t, k, qr, u, ql, qh);
    __syncthreads();
    build_level<3>(tree, w, k, qr, u, g);
    query_level<4>(tree, nemb, w, t, k, qr, u, ql, qh);
    __syncthreads();
    build_level<2>(tree, w, k, qr, u, g);
    query_level<3>(tree, nemb, w, t, k, qr, u, ql, qh);
    __syncthreads();
    build_level<1>(tree, w, k, qr, u, g);
    query_level<2>(tree, nemb, w, t, k, qr, u, ql, qh);
    __syncthreads();
    build_level<0>(tree, w, k, qr, u, g);
    query_level<1>(tree, nemb, w, t, k, qr, u, ql, qh);
    __syncthreads();
    query_level<0>(tree, nemb, w, t, k, qr, u, ql, qh);
    __syncthreads();

    // ---- output: out[b] = Q(root) @ W_lin.T ----
    if (t < NCC) {
        float acc = 0.f;
        #pragma unroll
        for (int d = 0; d < DD; ++d) acc = fmaf(tree[0][d], wl[d], acc);
        out[b * NCC + t] = acc;
    }
}

extern "C" void kernel_launch(void* const* d_in, const int* in_sizes, int n_in,
                              void* d_out, int out_size, void* d_ws, size_t ws_size,
                              hipStream_t stream) {
    const float* emb    = (const float*)d_in[0];
    const float* W_lin  = (const float*)d_in[1];
    const float* W_rule = (const float*)d_in[2];
    const int*   x      = (const int*)d_in[3];
    const int*   qlo    = (const int*)d_in[4];
    const int*   qhi    = (const int*)d_in[5];
    float* outp = (float*)d_out;

    int bsz = in_sizes[3] / LL;   // 2048
    seg_tree_kernel<<<dim3(bsz), dim3(64), 0, stream>>>(
        emb, W_lin, W_rule, x, qlo, qhi, outp);
}

// Round 5
// 15.330 us; speedup vs baseline: 2.7476x; 1.0650x over previous
//
#include <hip/hip_runtime.h>
#include <math.h>

#define DD 15          // feature dim
#define DP 20          // padded LDS row stride (80B, float4-aligned)
#define LL 64          // leaves
#define NCC 10         // num classes
#define NTREE 63       // internal nodes only (levels 0..5)
#define EPB 4          // batch elements per block (1 per wave)

// ---- DPP cross-lane (VALU pipe, no LDS) ----
__device__ __forceinline__ float dpp_xor1(float x) {   // quad_perm [1,0,3,2]
    return __int_as_float(__builtin_amdgcn_update_dpp(0, __float_as_int(x), 0xB1, 0xF, 0xF, true));
}
__device__ __forceinline__ float dpp_xor2(float x) {   // quad_perm [2,3,0,1]
    return __int_as_float(__builtin_amdgcn_update_dpp(0, __float_as_int(x), 0x4E, 0xF, 0xF, true));
}
__device__ __forceinline__ float dpp_hmirror(float x) { // row_half_mirror: u -> u^7 within 8
    return __int_as_float(__builtin_amdgcn_update_dpp(0, __float_as_int(x), 0x141, 0xF, 0xF, true));
}

// combine at one parent: 8 lanes cooperate.
// k = t&1 (W matrix), qr = (t>>1)&3 (4 A-rows), u = t&7 (2 output dims)
__device__ __forceinline__ void combine8_core(const float* Lrow, const float* Rrow,
                                              const float w[4][DD], int k, int qr, int u,
                                              float& o0, float& o1)
{
    float4 R0 = ((const float4*)Rrow)[0];
    float4 R1 = ((const float4*)Rrow)[1];
    float4 R2 = ((const float4*)Rrow)[2];
    float4 R3 = ((const float4*)Rrow)[3];          // .w = pad col15 = 0
    float4 Aq = ((const float4*)Lrow)[qr];         // A dims 4qr..4qr+3 (row15 pad = 0)
    float Bv[DD] = {R0.x,R0.y,R0.z,R0.w, R1.x,R1.y,R1.z,R1.w,
                    R2.x,R2.y,R2.z,R2.w, R3.x,R3.y,R3.z};
    float Av[4] = {Aq.x, Aq.y, Aq.z, Aq.w};

    float p = 0.f;
    #pragma unroll
    for (int ri = 0; ri < 4; ++ri) {
        float d0 = 0.f;
        #pragma unroll
        for (int j = 0; j < DD; ++j) d0 = fmaf(w[ri][j], Bv[j], d0);
        p = fmaf(Av[ri], d0, p);                   // invalid row 15: w==0, Av==0
    }
    // reduce partials over qr bits (1,2) and swap k — all DPP
    float a    = p + dpp_xor2(p);
    float hma  = dpp_hmirror(a);
    float self = a + dpp_xor1(hma);
    float oth  = dpp_xor1(a) + hma;
    float mx = fmaxf(self, oth);
    float es = __expf(self - mx), eo = __expf(oth - mx);
    float rs = __builtin_amdgcn_rcpf(es + eo);
    float aS = es * rs, aO = eo * rs;
    float a0 = (k == 0) ? aS : aO;                 // alpha for W0 (left child)
    float a1 = (k == 0) ? aO : aS;

    float2 lm = ((const float2*)Lrow)[u];          // dims 2u, 2u+1
    float2 rm = ((const float2*)Rrow)[u];
    float v0 = a0 * lm.x + a1 * rm.x;
    float v1 = a0 * lm.y + a1 * rm.y;              // u==7: dim15 = 0
    float ss = v0 * v0 + v1 * v1;
    ss += dpp_xor1(ss);
    ss += dpp_xor2(ss);
    ss += dpp_hmirror(ss);
    float inv = __builtin_amdgcn_rsqf(ss * (1.0f / DD) + 1e-6f);
    o0 = v0 * inv; o1 = v1 * inv;
}

// ---- build level 5: children are nemb rows selected by preloaded x indices ----
__device__ __forceinline__ void build_level5(float (*tw)[DP], const float (*nemb)[DP],
                                             const float w[4][DD],
                                             const int xA[4], const int xB[4],
                                             int k, int qr, int u, int g)
{
    #pragma unroll
    for (int st = 0; st < 4; ++st) {
        int pi = st * 8 + g;
        float o0, o1;
        combine8_core(&nemb[xA[st]][0], &nemb[xB[st]][0], w, k, qr, u, o0, o1);
        ((float2*)&tw[31 + pi][0])[u] = make_float2(o0, o1);
    }
}

// ---- query level 5: boundary nodes; children are leaves (nemb rows or inf) ----
__device__ __forceinline__ void query_level5(float (*tw)[DP], const float (*nemb)[DP],
                                             const float w[4][DD], int t, int k, int qr, int u,
                                             int ql, int qh, int xq1, int xq2)
{
    const int g2 = (t >> 3) & 1;
    int bnd = g2 ? qh : ql;
    int piB = bnd >> 1;
    int lo = 2 * piB, hi = lo + 1;
    bool full = (ql <= lo) && (qh >= hi);
    bool d1 = (ql > lo) || (qh < lo);
    bool d2 = (ql > hi) || (qh < hi);
    const float* Lrow = d1 ? &nemb[NCC][0] : &nemb[xq1][0];
    const float* Rrow = d2 ? &nemb[NCC][0] : &nemb[xq2][0];
    float o0, o1;
    combine8_core(Lrow, Rrow, w, k, qr, u, o0, o1);
    bool we = (!full) && (t < 16) && (g2 == 0 || piB != (ql >> 1));
    if (we) ((float2*)&tw[31 + piB][0])[u] = make_float2(o0, o1);
}

// ---- generic build (levels 1..4) ----
template<int LVL>
__device__ __forceinline__ void build_level(float (*tw)[DP], const float w[4][DD],
                                            int k, int qr, int u, int g)
{
    constexpr int n = 1 << LVL, first = n - 1, nst = (n + 7) / 8;
    #pragma unroll
    for (int st = 0; st < nst; ++st) {
        int pi0 = st * 8 + g;
        int pi = (n < 8) ? ((pi0 < n) ? pi0 : 0) : pi0;   // clamp keeps reads in-bounds
        int p = first + pi;
        float o0, o1;
        combine8_core(&tw[2 * p + 1][0], &tw[2 * p + 2][0], w, k, qr, u, o0, o1);
        if (pi0 < n)
            ((float2*)&tw[p][0])[u] = make_float2(o0, o1);
    }
}

// ---- generic query (levels 1..4): children in tree ----
template<int LVL>
__device__ __forceinline__ void query_level(float (*tw)[DP], const float (*nemb)[DP],
                                            const float w[4][DD], int t, int k, int qr, int u,
                                            int ql, int qh)
{
    constexpr int first = (1 << LVL) - 1;
    constexpr int sh = 6 - LVL;
    constexpr int shc = sh - 1;
    const int g2 = (t >> 3) & 1;
    int bnd = g2 ? qh : ql;
    int pi = bnd >> sh;
    int lo = pi << sh, hi = lo + (1 << sh) - 1;
    bool full = (ql <= lo) && (qh >= hi);
    int p = first + pi;
    int ci1 = 2 * pi, ci2 = 2 * pi + 1;
    int lo1 = ci1 << shc, hi1 = lo1 + (1 << shc) - 1;
    int lo2 = ci2 << shc, hi2 = lo2 + (1 << shc) - 1;
    bool d1 = (ql > hi1) || (qh < lo1);
    bool d2 = (ql > hi2) || (qh < lo2);
    const float* Lrow = d1 ? &nemb[NCC][0] : &tw[2 * p + 1][0];
    const float* Rrow = d2 ? &nemb[NCC][0] : &tw[2 * p + 2][0];
    float o0, o1;
    combine8_core(Lrow, Rrow, w, k, qr, u, o0, o1);
    bool we = (!full) && (t < 16) && (g2 == 0 || pi != (ql >> sh));
    if (we) ((float2*)&tw[p][0])[u] = make_float2(o0, o1);
}

// ---- query level 0: always write (covers the root-full case = build0) ----
__device__ __forceinline__ void query_level0(float (*tw)[DP], const float (*nemb)[DP],
                                             const float w[4][DD], int t, int k, int qr, int u,
                                             int ql, int qh)
{
    bool d1 = (ql > 31);             // left child [0,31]
    bool d2 = (qh < 32);             // right child [32,63]
    const float* Lrow = d1 ? &nemb[NCC][0] : &tw[1][0];
    const float* Rrow = d2 ? &nemb[NCC][0] : &tw[2][0];
    float o0, o1;
    combine8_core(Lrow, Rrow, w, k, qr, u, o0, o1);
    if (t < 8) ((float2*)&tw[0][0])[u] = make_float2(o0, o1);
}

extern "C" __global__ __attribute__((amdgpu_flat_work_group_size(256, 256)))
void seg_tree_kernel(
    const float* __restrict__ emb,
    const float* __restrict__ W_lin,
    const float* __restrict__ W_rule,
    const int*  __restrict__ x,
    const int*  __restrict__ qlo_g,
    const int*  __restrict__ qhi_g,
    float* __restrict__ out,
    int bsz)
{
    __shared__ __align__(16) float nemb[NCC + 1][DP];
    __shared__ __align__(16) float tree[EPB][NTREE][DP];

    const int tb = threadIdx.x;
    const int wv = tb >> 6;
    const int t  = tb & 63;
    int b = blockIdx.x * EPB + wv;
    const bool active = (b < bsz);
    if (!active) b = bsz - 1;                 // clamp: redundant work, store guarded

    const int k = t & 1, qr = (t >> 1) & 3, u = t & 7, g = t >> 3;
    float (*tw)[DP] = tree[wv];

    const int ql = qlo_g[b], qh = qhi_g[b];
    int xA[4], xB[4];
    #pragma unroll
    for (int st = 0; st < 4; ++st) {
        xA[st] = x[b * LL + st * 16 + 2 * g];
        xB[st] = x[b * LL + st * 16 + 2 * g + 1];
    }
    int piB = (((t >> 3) & 1) ? qh : ql) >> 1;
    int xq1 = x[b * LL + 2 * piB], xq2 = x[b * LL + 2 * piB + 1];

    // ---- per-lane weights: rows 4qr..4qr+3 of W_rule[k]; row 15 zeroed ----
    float w[4][DD];
    #pragma unroll
    for (int ri = 0; ri < 4; ++ri) {
        int i = 4 * qr + ri;
        bool valid = (i < DD);
        const float* src = W_rule + k * DD * DD + (valid ? i * DD : 0);
        #pragma unroll
        for (int j = 0; j < DD; ++j) w[ri][j] = valid ? src[j] : 0.0f;
    }
    #pragma unroll
    for (int ri = 0; ri < 4; ++ri)
        #pragma unroll
        for (int j = 0; j < DD; ++j)
            asm("" : "+v"(w[ri][j]));          // non-volatile pin: materialize once

    // ---- normalize emb rows into LDS once per block; pad col15 = 0 ----
    if (tb < NCC + 1) {
        float v[DD]; float ssum = 0.f;
        #pragma unroll
        for (int d = 0; d < DD; ++d) { v[d] = emb[tb * DD + d]; ssum += v[d] * v[d]; }
        float inv = __builtin_amdgcn_rsqf(ssum * (1.0f / DD) + 1e-6f);
        #pragma unroll
        for (int d = 0; d < DD; ++d) nemb[tb][d] = v[d] * inv;
        nemb[tb][DD] = 0.0f;
    }
    __syncthreads();                           // the only barrier

    // ---- 6 fused phases; waves fully independent, no barriers ----
    build_level5(tw, nemb, w, xA, xB, k, qr, u, g);
    query_level5(tw, nemb, w, t, k, qr, u, ql, qh, xq1, xq2);

    build_level<4>(tw, w, k, qr, u, g);
    query_level<4>(tw, nemb, w, t, k, qr, u, ql, qh);

    build_level<3>(tw, w, k, qr, u, g);
    query_level<3>(tw, nemb, w, t, k, qr, u, ql, qh);

    build_level<2>(tw, w, k, qr, u, g);
    query_level<2>(tw, nemb, w, t, k, qr, u, ql, qh);

    build_level<1>(tw, w, k, qr, u, g);
    query_level<1>(tw, nemb, w, t, k, qr, u, ql, qh);

    query_level0(tw, nemb, w, t, k, qr, u, ql, qh);

    // ---- output: out[b] = Q(root) @ W_lin.T ----
    if (active && t < NCC) {
        float acc = 0.f;
        #pragma unroll
        for (int d = 0; d < DD; ++d) acc = fmaf(tw[0][d], W_lin[t * DD + d], acc);
        out[b * NCC + t] = acc;
    }
}

extern "C" void kernel_launch(void* const* d_in, const int* in_sizes, int n_in,
                              void* d_out, int out_size, void* d_ws, size_t ws_size,
                              hipStream_t stream) {
    const float* emb    = (const float*)d_in[0];
    const float* W_lin  = (const float*)d_in[1];
    const float* W_rule = (const float*)d_in[2];
    const int*   x      = (const int*)d_in[3];
    const int*   qlo    = (const int*)d_in[4];
    const int*   qhi    = (const int*)d_in[5];
    float* outp = (float*)d_out;

    int bsz = in_sizes[3] / LL;               // 2048
    int nblk = (bsz + EPB - 1) / EPB;         // 512
    seg_tree_kernel<<<dim3(nblk), dim3(256), 0, stream>>>(
        emb, W_lin, W_rule, x, qlo, qhi, outp, bsz);
}